// Round 1
// baseline (1234.350 us; speedup 1.0000x reference)
//
#include <hip/hip_runtime.h>
#include <hip/hip_bf16.h>

typedef short bf16x8 __attribute__((ext_vector_type(8)));
typedef float f32x4 __attribute__((ext_vector_type(4)));

#define B_ 128
#define T_ 64
#define F_ 2048
#define N_ 1024
#define H_ 1024
#define C_ 22

__device__ __forceinline__ ushort f2bf(float f) {
    union { float f; unsigned u; } v; v.f = f;
    unsigned u = v.u;
    unsigned r = (u + 0x7FFFu + ((u >> 16) & 1u)) >> 16;
    return (ushort)r;
}
__device__ __forceinline__ float bf2f(ushort h) {
    union { unsigned u; float f; } v; v.u = ((unsigned)h) << 16;
    return v.f;
}

// ---------------- fp32 -> bf16 convert (vectorized) ----------------
__global__ __launch_bounds__(256) void cvt_f32_bf16(const float* __restrict__ in,
                                                    ushort* __restrict__ out, int n4) {
    int i = blockIdx.x * blockDim.x + threadIdx.x;
    if (i < n4) {
        float4 v = ((const float4*)in)[i];
        ushort4 o;
        o.x = f2bf(v.x); o.y = f2bf(v.y); o.z = f2bf(v.z); o.w = f2bf(v.w);
        ((ushort4*)out)[i] = o;
    }
}

// ---------------- async global->LDS, 16B per lane ----------------
__device__ __forceinline__ void gload16(const void* g, void* l) {
    __builtin_amdgcn_global_load_lds(
        (const __attribute__((address_space(1))) unsigned int*)g,
        (__attribute__((address_space(3))) unsigned int*)l, 16, 0, 0);
}

// ---------------- bf16 TN GEMM: C[m][n] = act(A[m][:] . B[n][:] + bias) ----------------
// 128x128 tile, BK=32, 4 waves each 64x64, m97 structure.
template<int K, bool RELU>
__global__ __launch_bounds__(256) void gemm_bt(const ushort* __restrict__ A,
                                               const ushort* __restrict__ Bm,
                                               const float* __restrict__ bias1,
                                               const float* __restrict__ bias2,
                                               ushort* __restrict__ C,
                                               int Nt, int Nn) {
    __shared__ ushort sA[128 * 32];
    __shared__ ushort sB[128 * 32];
    const int tid = threadIdx.x;
    const int lane = tid & 63, wv = tid >> 6;
    const int tm = blockIdx.x / Nt, tn = blockIdx.x % Nt;
    const int wm = wv >> 1, wn = wv & 1;

    const ushort* gA = A + (size_t)(tm * 128 + (tid >> 2)) * K + (tid & 3) * 8;
    const ushort* gB = Bm + (size_t)(tn * 128 + (tid >> 2)) * K + (tid & 3) * 8;
    char* lAb = (char*)sA + wv * 1024;
    char* lBb = (char*)sB + wv * 1024;

    f32x4 acc[4][4] = {};

    for (int kt = 0; kt < K / 32; kt++) {
        const ushort* a0 = gA + kt * 32;
        const ushort* b0 = gB + kt * 32;
        gload16(a0, lAb);
        gload16(a0 + 64 * K, lAb + 4096);
        gload16(b0, lBb);
        gload16(b0 + 64 * K, lBb + 4096);
        __syncthreads();

        bf16x8 af[4], bfv[4];
#pragma unroll
        for (int i = 0; i < 4; i++)
            af[i] = *(const bf16x8*)&sA[(wm * 64 + i * 16 + (lane & 15)) * 32 + (lane >> 4) * 8];
#pragma unroll
        for (int j = 0; j < 4; j++)
            bfv[j] = *(const bf16x8*)&sB[(wn * 64 + j * 16 + (lane & 15)) * 32 + (lane >> 4) * 8];
#pragma unroll
        for (int i = 0; i < 4; i++)
#pragma unroll
            for (int j = 0; j < 4; j++)
                acc[i][j] = __builtin_amdgcn_mfma_f32_16x16x32_bf16(af[i], bfv[j], acc[i][j], 0, 0, 0);
        __syncthreads();
    }

#pragma unroll
    for (int j = 0; j < 4; j++) {
        int n = tn * 128 + wn * 64 + j * 16 + (lane & 15);
        float bias = bias1[n] + (bias2 ? bias2[n] : 0.f);
#pragma unroll
        for (int i = 0; i < 4; i++) {
            int mbase = tm * 128 + wm * 64 + i * 16 + (lane >> 4) * 4;
#pragma unroll
            for (int r = 0; r < 4; r++) {
                float v = acc[i][j][r] + bias;
                if (RELU) v = v > 0.f ? v : 0.f;
                C[(size_t)(mbase + r) * Nn + n] = f2bf(v);
            }
        }
    }
}

// ---------------- one LSTM time step ----------------
// grid: 256 blocks = 4 batch-tiles x 64 hidden-tiles; block 256 thr; wave g computes gate g.
__global__ __launch_bounds__(256) void lstm_step(const ushort* __restrict__ hprev,
                                                 ushort* __restrict__ hnext,
                                                 float* __restrict__ cst,
                                                 const ushort* __restrict__ xg,
                                                 const ushort* __restrict__ Whh,
                                                 const int t) {
    const int tid = threadIdx.x;
    const int lane = tid & 63;
    const int g = tid >> 6;
    const int batch0 = (blockIdx.x >> 6) * 32;
    const int hid0 = (blockIdx.x & 63) * 16;

    const ushort* ar = hprev + (size_t)(batch0 + (lane & 15)) * H_ + ((lane >> 4) * 8);
    const ushort* br = Whh + (size_t)(g * H_ + hid0 + (lane & 15)) * H_ + ((lane >> 4) * 8);

    f32x4 acc0 = {}, acc1 = {};
#pragma unroll 8
    for (int ks = 0; ks < 32; ks++) {
        bf16x8 bfr = *(const bf16x8*)(br + ks * 32);
        bf16x8 a0 = *(const bf16x8*)(ar + ks * 32);
        bf16x8 a1 = *(const bf16x8*)(ar + 16 * H_ + ks * 32);
        acc0 = __builtin_amdgcn_mfma_f32_16x16x32_bf16(a0, bfr, acc0, 0, 0, 0);
        acc1 = __builtin_amdgcn_mfma_f32_16x16x32_bf16(a1, bfr, acc1, 0, 0, 0);
    }

    __shared__ float lg[4][32][16];
#pragma unroll
    for (int r = 0; r < 4; r++) {
        lg[g][(lane >> 4) * 4 + r][lane & 15] = acc0[r];
        lg[g][16 + (lane >> 4) * 4 + r][lane & 15] = acc1[r];
    }
    __syncthreads();

#pragma unroll
    for (int e = tid; e < 512; e += 256) {
        int bl = e >> 4, j = e & 15;
        int b = batch0 + bl, jj = hid0 + j;
        const ushort* xr = xg + (size_t)(b * 64 + t) * 4096;
        float pi = bf2f(xr[jj]) + lg[0][bl][j];
        float pf = bf2f(xr[1024 + jj]) + lg[1][bl][j];
        float pg = bf2f(xr[2048 + jj]) + lg[2][bl][j];
        float po = bf2f(xr[3072 + jj]) + lg[3][bl][j];
        float si = 1.f / (1.f + expf(-pi));
        float sf = 1.f / (1.f + expf(-pf));
        float tg = tanhf(pg);
        float so = 1.f / (1.f + expf(-po));
        size_t ci = (size_t)b * H_ + jj;
        float cn = sf * cst[ci] + si * tg;
        cst[ci] = cn;
        hnext[ci] = f2bf(so * tanhf(cn));
    }
}

// ---------------- final classifier ----------------
__global__ __launch_bounds__(256) void scores_k(const ushort* __restrict__ hs,
                                                const float* __restrict__ Wc,
                                                const float* __restrict__ bc,
                                                float* __restrict__ out) {
    int row = blockIdx.x * 8 + (threadIdx.x >> 5);
    int c = threadIdx.x & 31;
    int b = row >> 6, t = row & 63;
    const ushort* hr = hs + (size_t)(t + 1) * (B_ * H_) + (size_t)b * H_;
    if (c < C_) {
        const float* wr = Wc + c * 1024;
        float acc = 0.f;
        for (int k = 0; k < 1024; k += 8) {
            ushort4 h0 = *(const ushort4*)(hr + k);
            ushort4 h1 = *(const ushort4*)(hr + k + 4);
            float4 w0 = *(const float4*)(wr + k);
            float4 w1 = *(const float4*)(wr + k + 4);
            acc += bf2f(h0.x) * w0.x + bf2f(h0.y) * w0.y + bf2f(h0.z) * w0.z + bf2f(h0.w) * w0.w;
            acc += bf2f(h1.x) * w1.x + bf2f(h1.y) * w1.y + bf2f(h1.z) * w1.z + bf2f(h1.w) * w1.w;
        }
        out[(size_t)row * C_ + c] = acc + bc[c];
    }
}

extern "C" void kernel_launch(void* const* d_in, const int* in_sizes, int n_in,
                              void* d_out, int out_size, void* d_ws, size_t ws_size,
                              hipStream_t stream) {
    const float* x = (const float*)d_in[0];
    const float* W1 = (const float*)d_in[1];
    const float* b1 = (const float*)d_in[2];
    const float* W_ih = (const float*)d_in[3];
    const float* b_ih = (const float*)d_in[4];
    const float* W_hh = (const float*)d_in[5];
    const float* b_hh = (const float*)d_in[6];
    const float* Wc = (const float*)d_in[7];
    const float* bc = (const float*)d_in[8];
    float* out = (float*)d_out;

    char* ws = (char*)d_ws;
    ushort* Xb   = (ushort*)(ws);                 // 33,554,432 B  [8192][2048] bf16
    ushort* W1b  = (ushort*)(ws + 33554432);      //  4,194,304 B  [1024][2048]
    ushort* Wihb = (ushort*)(ws + 37748736);      //  8,388,608 B  [4096][1024]
    ushort* Whhb = (ushort*)(ws + 46137344);      //  8,388,608 B  [4096][1024]
    ushort* z    = (ushort*)(ws + 54525952);      // 16,777,216 B  [8192][1024]
    ushort* xg   = (ushort*)(ws + 71303168);      // 67,108,864 B  [8192][4096]
    ushort* hs   = (ushort*)(ws + 138412032);     // 17,039,360 B  [65][128][1024]
    float*  cst  = (float*)(ws + 155451392);      //    524,288 B  [128][1024] f32
    // total ws use: 155,975,680 B

    hipMemsetAsync(hs, 0, (size_t)B_ * H_ * sizeof(ushort), stream);   // h0 = 0
    hipMemsetAsync(cst, 0, (size_t)B_ * H_ * sizeof(float), stream);   // c0 = 0

    cvt_f32_bf16<<<16384, 256, 0, stream>>>(x, Xb, 4194304);
    cvt_f32_bf16<<<2048, 256, 0, stream>>>(W1, W1b, 524288);
    cvt_f32_bf16<<<4096, 256, 0, stream>>>(W_ih, Wihb, 1048576);
    cvt_f32_bf16<<<4096, 256, 0, stream>>>(W_hh, Whhb, 1048576);

    // z = relu(x @ W1^T + b1)           M=8192 N=1024 K=2048
    gemm_bt<2048, true><<<512, 256, 0, stream>>>(Xb, W1b, b1, nullptr, z, 8, 1024);
    // xg = z @ W_ih^T + (b_ih + b_hh)   M=8192 N=4096 K=1024
    gemm_bt<1024, false><<<2048, 256, 0, stream>>>(z, Wihb, b_ih, b_hh, xg, 32, 4096);

    for (int t = 0; t < T_; t++) {
        lstm_step<<<256, 256, 0, stream>>>(hs + (size_t)t * B_ * H_,
                                           hs + (size_t)(t + 1) * B_ * H_,
                                           cst, xg, Whhb, t);
    }

    scores_k<<<1024, 256, 0, stream>>>(hs, Wc, bc, out);
}